// Round 1
// baseline (1204.586 us; speedup 1.0000x reference)
//
#include <hip/hip_runtime.h>
#include <math.h>

// Problem constants (GATv2, 3 layers, H=4 heads, C=64 channels, D=64 in-dim)
#define HC   256   // H*C
#define DD   64
#define NHD  4
#define CC   64
#define NLAY 3

// ---------------------------------------------------------------------------
// zero counts/cursor/stats (ws is poisoned 0xAA before every call)
__global__ __launch_bounds__(256) void zero_kernel(int* __restrict__ counts,
                                                   int* __restrict__ cursor,
                                                   float* __restrict__ stats,
                                                   int n) {
    int i = blockIdx.x * 256 + threadIdx.x;
    if (i < n) { counts[i] = 0; cursor[i] = 0; }
    if (i < NLAY * 128) stats[i] = 0.f;
}

// histogram of destination nodes (self-loops appended implicitly)
__global__ __launch_bounds__(256) void count_kernel(const int* __restrict__ dstArr,
                                                    int* __restrict__ counts,
                                                    int e, int n) {
    int i = blockIdx.x * 256 + threadIdx.x;
    if (i >= e + n) return;
    int d = (i < e) ? dstArr[i] : (i - e);
    atomicAdd(&counts[d], 1);
}

// single-block exclusive scan -> rowptr[0..n]
__global__ __launch_bounds__(1024) void scan_kernel(const int* __restrict__ counts,
                                                    int* __restrict__ rowptr, int n) {
    __shared__ int ls[1024];
    int t = threadIdx.x;
    int chunk = (n + 1023) >> 10;
    int base = t * chunk;
    int local = 0;
    for (int i = 0; i < chunk; ++i) {
        int idx = base + i;
        if (idx < n) local += counts[idx];
    }
    ls[t] = local;
    __syncthreads();
    for (int off = 1; off < 1024; off <<= 1) {
        int v = (t >= off) ? ls[t - off] : 0;
        __syncthreads();
        ls[t] += v;
        __syncthreads();
    }
    int run = ls[t] - local;   // exclusive prefix for this thread's chunk
    for (int i = 0; i < chunk; ++i) {
        int idx = base + i;
        if (idx < n) { rowptr[idx] = run; run += counts[idx]; }
    }
    if (t == 1023) rowptr[n] = ls[1023];
}

// scatter edge sources into CSR slots grouped by destination
__global__ __launch_bounds__(256) void fill_kernel(const int* __restrict__ srcArr,
                                                   const int* __restrict__ dstArr,
                                                   const int* __restrict__ rowptr,
                                                   int* __restrict__ cursor,
                                                   int* __restrict__ csr_src,
                                                   int e, int n) {
    int i = blockIdx.x * 256 + threadIdx.x;
    if (i >= e + n) return;
    int s, d;
    if (i < e) { s = srcArr[i]; d = dstArr[i]; }
    else       { s = d = i - e; }
    int slot = rowptr[d] + atomicAdd(&cursor[d], 1);
    csr_src[slot] = s;
}

// ---------------------------------------------------------------------------
// xl = x @ Wl^T + bl ; xr = x @ Wr^T + br   (x: [n,64], W: [256,64])
// block = 256 threads (one output channel k each), 16 nodes per block.
// x reads are wave-uniform -> scalar loads; W rows stream via L1/L2.
__global__ __launch_bounds__(256) void proj_kernel(const float* __restrict__ x,
                                                   const float* __restrict__ Wl,
                                                   const float* __restrict__ bl,
                                                   const float* __restrict__ Wr,
                                                   const float* __restrict__ br,
                                                   float* __restrict__ xl,
                                                   float* __restrict__ xr, int n) {
    const int k  = threadIdx.x;          // 0..255
    const int n0 = blockIdx.x * 16;
    float accl[16], accr[16];
    const float bL = bl[k], bR = br[k];
    #pragma unroll
    for (int i = 0; i < 16; ++i) { accl[i] = bL; accr[i] = bR; }
    const float* wl = Wl + k * DD;
    const float* wr = Wr + k * DD;
    for (int d = 0; d < DD; ++d) {
        float wld = wl[d], wrd = wr[d];
        #pragma unroll
        for (int i = 0; i < 16; ++i) {
            int node = n0 + i;
            if (node >= n) node = n - 1;          // clamp (stores guarded below)
            float xv = x[node * DD + d];
            accl[i] += xv * wld;
            accr[i] += xv * wrd;
        }
    }
    #pragma unroll
    for (int i = 0; i < 16; ++i) {
        int node = n0 + i;
        if (node < n) {
            xl[node * HC + k] = accl[i];
            xr[node * HC + k] = accr[i];
        }
    }
}

// ---------------------------------------------------------------------------
// per-node attention: block = 4 waves = 4 heads, lane = channel.
// online softmax over incoming edges; head-mean + conv_bias -> h_out[n,64]
__global__ __launch_bounds__(256) void attn_kernel(const float* __restrict__ xl,
                                                   const float* __restrict__ xr,
                                                   const float* __restrict__ att,
                                                   const float* __restrict__ conv_bias,
                                                   const int* __restrict__ rowptr,
                                                   const int* __restrict__ csr_src,
                                                   float* __restrict__ h_out, int n) {
    const int node = blockIdx.x;
    const int hh = threadIdx.x >> 6;
    const int c  = threadIdx.x & 63;
    const float xr_v  = xr[node * HC + hh * CC + c];
    const float att_v = att[hh * CC + c];
    const int rs = rowptr[node];
    const int re = rowptr[node + 1];
    float m = -INFINITY, s = 0.f, acc = 0.f;
    for (int k = rs; k < re; ++k) {
        int j = csr_src[k];                       // wave-uniform
        float xl_v = xl[j * HC + hh * CC + c];    // coalesced 256B gather
        float t = xl_v + xr_v;
        t = (t > 0.f) ? t : 0.2f * t;             // leaky_relu
        float p = t * att_v;
        #pragma unroll
        for (int off = 32; off > 0; off >>= 1) p += __shfl_xor(p, off, 64);
        float nm = fmaxf(m, p);
        float f  = __expf(m - nm);                // exp(-inf)=0 on first edge
        float pe = __expf(p - nm);
        s   = s * f + pe;
        acc = acc * f + pe * xl_v;
        m = nm;
    }
    __shared__ float red[256];
    red[threadIdx.x] = acc / s;                   // deg>=1 (self-loop) -> s>0
    __syncthreads();
    if (threadIdx.x < 64) {
        float v = 0.25f * (red[c] + red[64 + c] + red[128 + c] + red[192 + c])
                + conv_bias[c];
        h_out[node * CC + c] = v;
    }
}

// ---------------------------------------------------------------------------
// per-channel sum / sumsq over nodes (hierarchical, 128 blocks)
__global__ __launch_bounds__(256) void stats_kernel(const float* __restrict__ h,
                                                    float* __restrict__ stats, int n) {
    int t = threadIdx.x;
    int c = t & 63, r = t >> 6;
    float s = 0.f, s2 = 0.f;
    for (int node = blockIdx.x * 4 + r; node < n; node += gridDim.x * 4) {
        float v = h[node * CC + c];
        s += v; s2 += v * v;
    }
    __shared__ float l1[256], l2[256];
    l1[t] = s; l2[t] = s2;
    __syncthreads();
    if (t < 64) {
        s  = l1[t] + l1[64 + t] + l1[128 + t] + l1[192 + t];
        s2 = l2[t] + l2[64 + t] + l2[128 + t] + l2[192 + t];
        atomicAdd(&stats[c], s);
        atomicAdd(&stats[64 + c], s2);
    }
}

// GraphNorm: x = (h - alpha*mu) * rsqrt(var+eps) * w + b
// var = E[h^2] - 2*alpha*mu^2 + alpha^2*mu^2  (since E[h]=mu)
__global__ __launch_bounds__(256) void norm_kernel(const float* __restrict__ h,
                                                   const float* __restrict__ stats,
                                                   const float* __restrict__ gw,
                                                   const float* __restrict__ gs,
                                                   const float* __restrict__ gb,
                                                   float* __restrict__ out, int n) {
    int c = threadIdx.x & 63;
    float inv_n = 1.0f / (float)n;
    float mu  = stats[c] * inv_n;
    float eh2 = stats[64 + c] * inv_n;
    float a   = gs[c];
    float var = eh2 - 2.f * a * mu * mu + a * a * mu * mu;
    float rstd = rsqrtf(var + 1e-5f);
    float w = gw[c] * rstd;
    float b = gb[c];
    float off = a * mu;
    int total = n * CC;
    for (int idx = blockIdx.x * 256 + threadIdx.x; idx < total; idx += gridDim.x * 256)
        out[idx] = (h[idx] - off) * w + b;
}

// ---------------------------------------------------------------------------
extern "C" void kernel_launch(void* const* d_in, const int* in_sizes, int n_in,
                              void* d_out, int out_size, void* d_ws, size_t ws_size,
                              hipStream_t stream) {
    const float* x0  = (const float*)d_in[0];
    const int*   ei  = (const int*)d_in[1];
    const float* Wl  = (const float*)d_in[2];
    const float* bl  = (const float*)d_in[3];
    const float* Wr  = (const float*)d_in[4];
    const float* br  = (const float*)d_in[5];
    const float* att = (const float*)d_in[6];
    const float* cb  = (const float*)d_in[7];
    const float* gw  = (const float*)d_in[8];
    const float* gs  = (const float*)d_in[9];
    const float* gb  = (const float*)d_in[10];

    const int n = in_sizes[0] / DD;      // 25000
    const int e = in_sizes[1] / 2;       // 400000
    const int* srcArr = ei;
    const int* dstArr = ei + e;

    // carve workspace
    char* w = (char*)d_ws;
    auto alloc = [&](size_t bytes) -> char* {
        char* p = w;
        w += (bytes + 255) & ~(size_t)255;
        return p;
    };
    float* xl     = (float*)alloc((size_t)n * HC * 4);
    float* xr     = (float*)alloc((size_t)n * HC * 4);
    float* hbuf   = (float*)alloc((size_t)n * CC * 4);
    float* xbuf   = (float*)alloc((size_t)n * CC * 4);
    int*   counts = (int*)  alloc((size_t)n * 4);
    int*   cursor = (int*)  alloc((size_t)n * 4);
    int*   rowptr = (int*)  alloc((size_t)(n + 1) * 4);
    int*   csr    = (int*)  alloc((size_t)(e + n) * 4);
    float* stats  = (float*)alloc(NLAY * 128 * 4);

    const int tot = e + n;
    hipLaunchKernelGGL(zero_kernel,  dim3((n + 255) / 256),   dim3(256), 0, stream,
                       counts, cursor, stats, n);
    hipLaunchKernelGGL(count_kernel, dim3((tot + 255) / 256), dim3(256), 0, stream,
                       dstArr, counts, e, n);
    hipLaunchKernelGGL(scan_kernel,  dim3(1), dim3(1024), 0, stream,
                       counts, rowptr, n);
    hipLaunchKernelGGL(fill_kernel,  dim3((tot + 255) / 256), dim3(256), 0, stream,
                       srcArr, dstArr, rowptr, cursor, csr, e, n);

    const float* xin = x0;
    for (int L = 0; L < NLAY; ++L) {
        hipLaunchKernelGGL(proj_kernel, dim3((n + 15) / 16), dim3(256), 0, stream,
                           xin, Wl + (size_t)L * HC * DD, bl + L * HC,
                           Wr + (size_t)L * HC * DD, br + L * HC, xl, xr, n);
        hipLaunchKernelGGL(attn_kernel, dim3(n), dim3(256), 0, stream,
                           xl, xr, att + L * HC, cb + L * CC, rowptr, csr, hbuf, n);
        hipLaunchKernelGGL(stats_kernel, dim3(128), dim3(256), 0, stream,
                           hbuf, stats + L * 128, n);
        float* xout = (L == NLAY - 1) ? (float*)d_out : xbuf;
        hipLaunchKernelGGL(norm_kernel, dim3(512), dim3(256), 0, stream,
                           hbuf, stats + L * 128, gw + L * CC, gs + L * CC, gb + L * CC,
                           xout, n);
        xin = xbuf;
    }
}

// Round 2
// 761.502 us; speedup vs baseline: 1.5819x; 1.5819x over previous
//
#include <hip/hip_runtime.h>
#include <math.h>

// Problem constants (GATv2, 3 layers, H=4 heads, C=64 channels, D=64 in-dim)
#define HC   256   // H*C
#define DD   64
#define NHD  4
#define CC   64
#define NLAY 3

// ---------------------------------------------------------------------------
// zero counts/cursor/stats (ws is poisoned 0xAA before every call)
__global__ __launch_bounds__(256) void zero_kernel(int* __restrict__ counts,
                                                   int* __restrict__ cursor,
                                                   float* __restrict__ stats,
                                                   int n) {
    int i = blockIdx.x * 256 + threadIdx.x;
    if (i < n) { counts[i] = 0; cursor[i] = 0; }
    if (i < NLAY * 128) stats[i] = 0.f;
}

// histogram of destination nodes (self-loops appended implicitly)
__global__ __launch_bounds__(256) void count_kernel(const int* __restrict__ dstArr,
                                                    int* __restrict__ counts,
                                                    int e, int n) {
    int i = blockIdx.x * 256 + threadIdx.x;
    if (i >= e + n) return;
    int d = (i < e) ? dstArr[i] : (i - e);
    atomicAdd(&counts[d], 1);
}

// single-block exclusive scan -> rowptr[0..n]
__global__ __launch_bounds__(1024) void scan_kernel(const int* __restrict__ counts,
                                                    int* __restrict__ rowptr, int n) {
    __shared__ int ls[1024];
    int t = threadIdx.x;
    int chunk = (n + 1023) >> 10;
    int base = t * chunk;
    int local = 0;
    for (int i = 0; i < chunk; ++i) {
        int idx = base + i;
        if (idx < n) local += counts[idx];
    }
    ls[t] = local;
    __syncthreads();
    for (int off = 1; off < 1024; off <<= 1) {
        int v = (t >= off) ? ls[t - off] : 0;
        __syncthreads();
        ls[t] += v;
        __syncthreads();
    }
    int run = ls[t] - local;   // exclusive prefix for this thread's chunk
    for (int i = 0; i < chunk; ++i) {
        int idx = base + i;
        if (idx < n) { rowptr[idx] = run; run += counts[idx]; }
    }
    if (t == 1023) rowptr[n] = ls[1023];
}

// scatter edge sources into CSR slots grouped by destination
__global__ __launch_bounds__(256) void fill_kernel(const int* __restrict__ srcArr,
                                                   const int* __restrict__ dstArr,
                                                   const int* __restrict__ rowptr,
                                                   int* __restrict__ cursor,
                                                   int* __restrict__ csr_src,
                                                   int e, int n) {
    int i = blockIdx.x * 256 + threadIdx.x;
    if (i >= e + n) return;
    int s, d;
    if (i < e) { s = srcArr[i]; d = dstArr[i]; }
    else       { s = d = i - e; }
    int slot = rowptr[d] + atomicAdd(&cursor[d], 1);
    csr_src[slot] = s;
}

// ---------------------------------------------------------------------------
// xl = x @ Wl^T + bl ; xr = x @ Wr^T + br  (x:[n,64], W:[256,64])
// LDS-tiled: block = 256 thr computes 64 nodes x 64 channels for BOTH W's.
// tx=c (0..63) = channel-in-tile (lane id -> coalesced/conflict-free W reads),
// ty (0..3) = node group of 16 (wave-uniform -> x reads are LDS broadcasts).
__global__ __launch_bounds__(256) void proj_kernel(const float* __restrict__ x,
                                                   const float* __restrict__ Wl,
                                                   const float* __restrict__ bl,
                                                   const float* __restrict__ Wr,
                                                   const float* __restrict__ br,
                                                   float* __restrict__ xl,
                                                   float* __restrict__ xr, int n) {
    __shared__ float xs[64 * 64];        // x tile  [node][d]
    __shared__ float wlT[64 * 65];       // Wl tile [d][c], pad 65 -> no conflicts
    __shared__ float wrT[64 * 65];
    const int t  = threadIdx.x;
    const int c  = t & 63;
    const int ty = t >> 6;
    const int n0 = blockIdx.x * 64;
    const int cb = blockIdx.y * 64;      // channel tile base (0,64,128,192)

    // stage x tile: 4096 contiguous floats, coalesced float4, zero-fill tail
    {
        const float* xb = x + (size_t)n0 * DD;
        const int limit = (n - n0) * DD;               // valid floats in tile
        #pragma unroll
        for (int k = 0; k < 4; ++k) {
            int f = (k * 256 + t) * 4;                 // float index
            float4 v = make_float4(0.f, 0.f, 0.f, 0.f);
            if (f + 3 < limit) v = *(const float4*)(xb + f);
            else {                                     // ragged tail
                float tmp[4] = {0.f, 0.f, 0.f, 0.f};
                for (int q = 0; q < 4; ++q) if (f + q < limit) tmp[q] = xb[f + q];
                v = make_float4(tmp[0], tmp[1], tmp[2], tmp[3]);
            }
            *(float4*)&xs[f] = v;
        }
    }
    // stage W tiles transposed: flat f -> cc=f/64, dd=f%64 -> wT[dd*65+cc]
    {
        const float* wlb = Wl + (size_t)cb * DD;
        const float* wrb = Wr + (size_t)cb * DD;
        #pragma unroll
        for (int k = 0; k < 16; ++k) {
            int f = k * 256 + t;
            int ccc = f >> 6, ddd = f & 63;
            wlT[ddd * 65 + ccc] = wlb[f];
            wrT[ddd * 65 + ccc] = wrb[f];
        }
    }
    __syncthreads();

    float accl[16], accr[16];
    {
        const float bL = bl[cb + c], bR = br[cb + c];
        #pragma unroll
        for (int i = 0; i < 16; ++i) { accl[i] = bL; accr[i] = bR; }
    }
    const float* xrow = xs + ty * 16 * DD;
    for (int d4 = 0; d4 < DD; d4 += 4) {
        float4 xv[16];
        #pragma unroll
        for (int i = 0; i < 16; ++i)
            xv[i] = *(const float4*)(xrow + i * DD + d4);   // broadcast reads
        #pragma unroll
        for (int dd = 0; dd < 4; ++dd) {
            float wlv = wlT[(d4 + dd) * 65 + c];
            float wrv = wrT[(d4 + dd) * 65 + c];
            #pragma unroll
            for (int i = 0; i < 16; ++i) {
                float xvv = ((const float*)&xv[i])[dd];
                accl[i] = fmaf(xvv, wlv, accl[i]);
                accr[i] = fmaf(xvv, wrv, accr[i]);
            }
        }
    }
    #pragma unroll
    for (int i = 0; i < 16; ++i) {
        int node = n0 + ty * 16 + i;
        if (node < n) {
            xl[(size_t)node * HC + cb + c] = accl[i];
            xr[(size_t)node * HC + cb + c] = accr[i];
        }
    }
}

// ---------------------------------------------------------------------------
// per-node attention: block = 4 waves = 4 heads, lane = channel.
// online softmax over incoming edges; head-mean + conv_bias -> h_out[n,64]
__global__ __launch_bounds__(256) void attn_kernel(const float* __restrict__ xl,
                                                   const float* __restrict__ xr,
                                                   const float* __restrict__ att,
                                                   const float* __restrict__ conv_bias,
                                                   const int* __restrict__ rowptr,
                                                   const int* __restrict__ csr_src,
                                                   float* __restrict__ h_out, int n) {
    const int node = blockIdx.x;
    const int hh = threadIdx.x >> 6;
    const int c  = threadIdx.x & 63;
    const float xr_v  = xr[node * HC + hh * CC + c];
    const float att_v = att[hh * CC + c];
    const int rs = rowptr[node];
    const int re = rowptr[node + 1];
    float m = -INFINITY, s = 0.f, acc = 0.f;
    for (int k = rs; k < re; ++k) {
        int j = csr_src[k];                       // wave-uniform
        float xl_v = xl[j * HC + hh * CC + c];    // coalesced 256B gather
        float t = xl_v + xr_v;
        t = (t > 0.f) ? t : 0.2f * t;             // leaky_relu
        float p = t * att_v;
        #pragma unroll
        for (int off = 32; off > 0; off >>= 1) p += __shfl_xor(p, off, 64);
        float nm = fmaxf(m, p);
        float f  = __expf(m - nm);                // exp(-inf)=0 on first edge
        float pe = __expf(p - nm);
        s   = s * f + pe;
        acc = acc * f + pe * xl_v;
        m = nm;
    }
    __shared__ float red[256];
    red[threadIdx.x] = acc / s;                   // deg>=1 (self-loop) -> s>0
    __syncthreads();
    if (threadIdx.x < 64) {
        float v = 0.25f * (red[c] + red[64 + c] + red[128 + c] + red[192 + c])
                + conv_bias[c];
        h_out[node * CC + c] = v;
    }
}

// ---------------------------------------------------------------------------
// per-channel sum / sumsq over nodes (hierarchical, 128 blocks)
__global__ __launch_bounds__(256) void stats_kernel(const float* __restrict__ h,
                                                    float* __restrict__ stats, int n) {
    int t = threadIdx.x;
    int c = t & 63, r = t >> 6;
    float s = 0.f, s2 = 0.f;
    for (int node = blockIdx.x * 4 + r; node < n; node += gridDim.x * 4) {
        float v = h[node * CC + c];
        s += v; s2 += v * v;
    }
    __shared__ float l1[256], l2[256];
    l1[t] = s; l2[t] = s2;
    __syncthreads();
    if (t < 64) {
        s  = l1[t] + l1[64 + t] + l1[128 + t] + l1[192 + t];
        s2 = l2[t] + l2[64 + t] + l2[128 + t] + l2[192 + t];
        atomicAdd(&stats[c], s);
        atomicAdd(&stats[64 + c], s2);
    }
}

// GraphNorm: x = (h - alpha*mu) * rsqrt(var+eps) * w + b
// var = E[h^2] - 2*alpha*mu^2 + alpha^2*mu^2  (since E[h]=mu)
__global__ __launch_bounds__(256) void norm_kernel(const float* __restrict__ h,
                                                   const float* __restrict__ stats,
                                                   const float* __restrict__ gw,
                                                   const float* __restrict__ gs,
                                                   const float* __restrict__ gb,
                                                   float* __restrict__ out, int n) {
    int c = threadIdx.x & 63;
    float inv_n = 1.0f / (float)n;
    float mu  = stats[c] * inv_n;
    float eh2 = stats[64 + c] * inv_n;
    float a   = gs[c];
    float var = eh2 - 2.f * a * mu * mu + a * a * mu * mu;
    float rstd = rsqrtf(var + 1e-5f);
    float w = gw[c] * rstd;
    float b = gb[c];
    float off = a * mu;
    int total = n * CC;
    for (int idx = blockIdx.x * 256 + threadIdx.x; idx < total; idx += gridDim.x * 256)
        out[idx] = (h[idx] - off) * w + b;
}

// ---------------------------------------------------------------------------
extern "C" void kernel_launch(void* const* d_in, const int* in_sizes, int n_in,
                              void* d_out, int out_size, void* d_ws, size_t ws_size,
                              hipStream_t stream) {
    const float* x0  = (const float*)d_in[0];
    const int*   ei  = (const int*)d_in[1];
    const float* Wl  = (const float*)d_in[2];
    const float* bl  = (const float*)d_in[3];
    const float* Wr  = (const float*)d_in[4];
    const float* br  = (const float*)d_in[5];
    const float* att = (const float*)d_in[6];
    const float* cb  = (const float*)d_in[7];
    const float* gw  = (const float*)d_in[8];
    const float* gs  = (const float*)d_in[9];
    const float* gb  = (const float*)d_in[10];

    const int n = in_sizes[0] / DD;      // 25000
    const int e = in_sizes[1] / 2;       // 400000
    const int* srcArr = ei;
    const int* dstArr = ei + e;

    // carve workspace
    char* w = (char*)d_ws;
    auto alloc = [&](size_t bytes) -> char* {
        char* p = w;
        w += (bytes + 255) & ~(size_t)255;
        return p;
    };
    float* xl     = (float*)alloc((size_t)n * HC * 4);
    float* xr     = (float*)alloc((size_t)n * HC * 4);
    float* hbuf   = (float*)alloc((size_t)n * CC * 4);
    float* xbuf   = (float*)alloc((size_t)n * CC * 4);
    int*   counts = (int*)  alloc((size_t)n * 4);
    int*   cursor = (int*)  alloc((size_t)n * 4);
    int*   rowptr = (int*)  alloc((size_t)(n + 1) * 4);
    int*   csr    = (int*)  alloc((size_t)(e + n) * 4);
    float* stats  = (float*)alloc(NLAY * 128 * 4);

    const int tot = e + n;
    hipLaunchKernelGGL(zero_kernel,  dim3((n + 255) / 256),   dim3(256), 0, stream,
                       counts, cursor, stats, n);
    hipLaunchKernelGGL(count_kernel, dim3((tot + 255) / 256), dim3(256), 0, stream,
                       dstArr, counts, e, n);
    hipLaunchKernelGGL(scan_kernel,  dim3(1), dim3(1024), 0, stream,
                       counts, rowptr, n);
    hipLaunchKernelGGL(fill_kernel,  dim3((tot + 255) / 256), dim3(256), 0, stream,
                       srcArr, dstArr, rowptr, cursor, csr, e, n);

    const float* xin = x0;
    for (int L = 0; L < NLAY; ++L) {
        hipLaunchKernelGGL(proj_kernel, dim3((n + 63) / 64, 4), dim3(256), 0, stream,
                           xin, Wl + (size_t)L * HC * DD, bl + L * HC,
                           Wr + (size_t)L * HC * DD, br + L * HC, xl, xr, n);
        hipLaunchKernelGGL(attn_kernel, dim3(n), dim3(256), 0, stream,
                           xl, xr, att + L * HC, cb + L * CC, rowptr, csr, hbuf, n);
        hipLaunchKernelGGL(stats_kernel, dim3(128), dim3(256), 0, stream,
                           hbuf, stats + L * 128, n);
        float* xout = (L == NLAY - 1) ? (float*)d_out : xbuf;
        hipLaunchKernelGGL(norm_kernel, dim3(512), dim3(256), 0, stream,
                           hbuf, stats + L * 128, gw + L * CC, gs + L * CC, gb + L * CC,
                           xout, n);
        xin = xbuf;
    }
}

// Round 3
// 515.222 us; speedup vs baseline: 2.3380x; 1.4780x over previous
//
#include <hip/hip_runtime.h>
#include <hip/hip_fp16.h>
#include <math.h>

// Problem constants (GATv2, 3 layers, H=4 heads, C=64 channels, D=64 in-dim)
#define HC   256   // H*C
#define DD   64
#define NHD  4
#define CC   64
#define NLAY 3

// ---------------------------------------------------------------------------
// zero counts/cursor/stats (ws is poisoned 0xAA before every call)
__global__ __launch_bounds__(256) void zero_kernel(int* __restrict__ counts,
                                                   int* __restrict__ cursor,
                                                   float* __restrict__ stats,
                                                   int n) {
    int i = blockIdx.x * 256 + threadIdx.x;
    if (i < n) { counts[i] = 0; cursor[i] = 0; }
    if (i < NLAY * 128) stats[i] = 0.f;
}

// histogram of destination nodes (self-loops appended implicitly)
__global__ __launch_bounds__(256) void count_kernel(const int* __restrict__ dstArr,
                                                    int* __restrict__ counts,
                                                    int e, int n) {
    int i = blockIdx.x * 256 + threadIdx.x;
    if (i >= e + n) return;
    int d = (i < e) ? dstArr[i] : (i - e);
    atomicAdd(&counts[d], 1);
}

// single-block exclusive scan -> rowptr[0..n]
__global__ __launch_bounds__(1024) void scan_kernel(const int* __restrict__ counts,
                                                    int* __restrict__ rowptr, int n) {
    __shared__ int ls[1024];
    int t = threadIdx.x;
    int chunk = (n + 1023) >> 10;
    int base = t * chunk;
    int local = 0;
    for (int i = 0; i < chunk; ++i) {
        int idx = base + i;
        if (idx < n) local += counts[idx];
    }
    ls[t] = local;
    __syncthreads();
    for (int off = 1; off < 1024; off <<= 1) {
        int v = (t >= off) ? ls[t - off] : 0;
        __syncthreads();
        ls[t] += v;
        __syncthreads();
    }
    int run = ls[t] - local;   // exclusive prefix for this thread's chunk
    for (int i = 0; i < chunk; ++i) {
        int idx = base + i;
        if (idx < n) { rowptr[idx] = run; run += counts[idx]; }
    }
    if (t == 1023) rowptr[n] = ls[1023];
}

// scatter edge sources into CSR slots grouped by destination
__global__ __launch_bounds__(256) void fill_kernel(const int* __restrict__ srcArr,
                                                   const int* __restrict__ dstArr,
                                                   const int* __restrict__ rowptr,
                                                   int* __restrict__ cursor,
                                                   int* __restrict__ csr_src,
                                                   int e, int n) {
    int i = blockIdx.x * 256 + threadIdx.x;
    if (i >= e + n) return;
    int s, d;
    if (i < e) { s = srcArr[i]; d = dstArr[i]; }
    else       { s = d = i - e; }
    int slot = rowptr[d] + atomicAdd(&cursor[d], 1);
    csr_src[slot] = s;
}

// ---------------------------------------------------------------------------
// xl = x @ Wl^T + bl (fp16 out) ; xr = x @ Wr^T + br (f32 out)
// LDS-tiled: block = 256 thr computes 64 nodes x 64 channels for BOTH W's.
__global__ __launch_bounds__(256) void proj_kernel(const float* __restrict__ x,
                                                   const float* __restrict__ Wl,
                                                   const float* __restrict__ bl,
                                                   const float* __restrict__ Wr,
                                                   const float* __restrict__ br,
                                                   __half* __restrict__ xl,
                                                   float* __restrict__ xr, int n) {
    __shared__ float xs[64 * 64];        // x tile  [node][d]
    __shared__ float wlT[64 * 65];       // Wl tile [d][c], pad 65 -> no conflicts
    __shared__ float wrT[64 * 65];
    const int t  = threadIdx.x;
    const int c  = t & 63;
    const int ty = t >> 6;
    const int n0 = blockIdx.x * 64;
    const int cb = blockIdx.y * 64;      // channel tile base (0,64,128,192)

    // stage x tile: 4096 contiguous floats, coalesced float4, zero-fill tail
    {
        const float* xb = x + (size_t)n0 * DD;
        const int limit = (n - n0) * DD;               // valid floats in tile
        #pragma unroll
        for (int k = 0; k < 4; ++k) {
            int f = (k * 256 + t) * 4;                 // float index
            float4 v = make_float4(0.f, 0.f, 0.f, 0.f);
            if (f + 3 < limit) v = *(const float4*)(xb + f);
            else {                                     // ragged tail
                float tmp[4] = {0.f, 0.f, 0.f, 0.f};
                for (int q = 0; q < 4; ++q) if (f + q < limit) tmp[q] = xb[f + q];
                v = make_float4(tmp[0], tmp[1], tmp[2], tmp[3]);
            }
            *(float4*)&xs[f] = v;
        }
    }
    // stage W tiles transposed: flat f -> cc=f/64, dd=f%64 -> wT[dd*65+cc]
    {
        const float* wlb = Wl + (size_t)cb * DD;
        const float* wrb = Wr + (size_t)cb * DD;
        #pragma unroll
        for (int k = 0; k < 16; ++k) {
            int f = k * 256 + t;
            int ccc = f >> 6, ddd = f & 63;
            wlT[ddd * 65 + ccc] = wlb[f];
            wrT[ddd * 65 + ccc] = wrb[f];
        }
    }
    __syncthreads();

    float accl[16], accr[16];
    {
        const float bL = bl[cb + c], bR = br[cb + c];
        #pragma unroll
        for (int i = 0; i < 16; ++i) { accl[i] = bL; accr[i] = bR; }
    }
    const float* xrow = xs + ty * 16 * DD;
    for (int d4 = 0; d4 < DD; d4 += 4) {
        float4 xv[16];
        #pragma unroll
        for (int i = 0; i < 16; ++i)
            xv[i] = *(const float4*)(xrow + i * DD + d4);   // broadcast reads
        #pragma unroll
        for (int dd = 0; dd < 4; ++dd) {
            float wlv = wlT[(d4 + dd) * 65 + c];
            float wrv = wrT[(d4 + dd) * 65 + c];
            #pragma unroll
            for (int i = 0; i < 16; ++i) {
                float xvv = ((const float*)&xv[i])[dd];
                accl[i] = fmaf(xvv, wlv, accl[i]);
                accr[i] = fmaf(xvv, wrv, accr[i]);
            }
        }
    }
    #pragma unroll
    for (int i = 0; i < 16; ++i) {
        int node = n0 + ty * 16 + i;
        if (node < n) {
            xl[(size_t)node * HC + cb + c] = __float2half(accl[i]);
            xr[(size_t)node * HC + cb + c] = accr[i];
        }
    }
}

// ---------------------------------------------------------------------------
// per-node attention: ONE wave per node handles ALL 4 heads.
// lane l: head h = l>>4, channels (l&15)*4 .. +3  (row offset = l*4).
// online softmax per 16-lane head-group; head-mean via 2 shuffles; no LDS.
__global__ __launch_bounds__(256) void attn_kernel(const __half* __restrict__ xl,
                                                   const float* __restrict__ xr,
                                                   const float* __restrict__ att,
                                                   const float* __restrict__ conv_bias,
                                                   const int* __restrict__ rowptr,
                                                   const int* __restrict__ csr_src,
                                                   float* __restrict__ h_out, int n) {
    const int wave = threadIdx.x >> 6;
    const int l    = threadIdx.x & 63;
    const int v    = blockIdx.x * 4 + wave;
    if (v >= n) return;

    const float4 xr4 = *(const float4*)(xr + (size_t)v * HC + l * 4);
    const float4 at4 = *(const float4*)(att + l * 4);
    const int rs = rowptr[v];
    const int re = rowptr[v + 1];

    float m = -INFINITY, s = 0.f;
    float4 acc = make_float4(0.f, 0.f, 0.f, 0.f);

    // software pipeline: row gather for edge k+1 issued while computing edge k
    int   j   = csr_src[rs];
    float2 raw = *(const float2*)(xl + (size_t)j * HC + l * 4);   // 4 halves
    for (int k = rs; k < re; ++k) {
        float2 rawn = raw;
        if (k + 1 < re) {
            int jn = csr_src[k + 1];
            rawn = *(const float2*)(xl + (size_t)jn * HC + l * 4);
        }
        const __half2 h0 = *(const __half2*)&raw.x;
        const __half2 h1 = *(const __half2*)&raw.y;
        const float2 f0 = __half22float2(h0);
        const float2 f1 = __half22float2(h1);
        float xlv[4] = { f0.x, f0.y, f1.x, f1.y };

        float p = 0.f;
        #pragma unroll
        for (int q = 0; q < 4; ++q) {
            float t = xlv[q] + ((const float*)&xr4)[q];
            t = fmaxf(t, 0.2f * t);                    // leaky_relu
            p = fmaf(t, ((const float*)&at4)[q], p);
        }
        // reduce over the 16-lane head group
        p += __shfl_xor(p, 1, 64);
        p += __shfl_xor(p, 2, 64);
        p += __shfl_xor(p, 4, 64);
        p += __shfl_xor(p, 8, 64);

        float nm = fmaxf(m, p);
        float f  = __expf(m - nm);                     // exp(-inf)=0 first edge
        float pe = __expf(p - nm);
        s = s * f + pe;
        #pragma unroll
        for (int q = 0; q < 4; ++q)
            ((float*)&acc)[q] = fmaf(((float*)&acc)[q], f, pe * xlv[q]);
        m = nm;
        raw = rawn;
    }

    const float inv = 1.f / s;                         // deg>=1 (self-loop)
    #pragma unroll
    for (int q = 0; q < 4; ++q) {
        float a = ((float*)&acc)[q] * inv;
        a += __shfl_xor(a, 16, 64);                    // sum over heads
        a += __shfl_xor(a, 32, 64);
        ((float*)&acc)[q] = a;
    }
    if (l < 16) {
        const float4 cb4 = *(const float4*)(conv_bias + l * 4);
        float4 o;
        o.x = 0.25f * acc.x + cb4.x;
        o.y = 0.25f * acc.y + cb4.y;
        o.z = 0.25f * acc.z + cb4.z;
        o.w = 0.25f * acc.w + cb4.w;
        *(float4*)(h_out + (size_t)v * CC + l * 4) = o;
    }
}

// ---------------------------------------------------------------------------
// per-channel sum / sumsq over nodes (hierarchical, 128 blocks)
__global__ __launch_bounds__(256) void stats_kernel(const float* __restrict__ h,
                                                    float* __restrict__ stats, int n) {
    int t = threadIdx.x;
    int c = t & 63, r = t >> 6;
    float s = 0.f, s2 = 0.f;
    for (int node = blockIdx.x * 4 + r; node < n; node += gridDim.x * 4) {
        float v = h[node * CC + c];
        s += v; s2 += v * v;
    }
    __shared__ float l1[256], l2[256];
    l1[t] = s; l2[t] = s2;
    __syncthreads();
    if (t < 64) {
        s  = l1[t] + l1[64 + t] + l1[128 + t] + l1[192 + t];
        s2 = l2[t] + l2[64 + t] + l2[128 + t] + l2[192 + t];
        atomicAdd(&stats[c], s);
        atomicAdd(&stats[64 + c], s2);
    }
}

// GraphNorm: x = (h - alpha*mu) * rsqrt(var+eps) * w + b
// var = E[h^2] - 2*alpha*mu^2 + alpha^2*mu^2  (since E[h]=mu)
__global__ __launch_bounds__(256) void norm_kernel(const float* __restrict__ h,
                                                   const float* __restrict__ stats,
                                                   const float* __restrict__ gw,
                                                   const float* __restrict__ gs,
                                                   const float* __restrict__ gb,
                                                   float* __restrict__ out, int n) {
    int c = threadIdx.x & 63;
    float inv_n = 1.0f / (float)n;
    float mu  = stats[c] * inv_n;
    float eh2 = stats[64 + c] * inv_n;
    float a   = gs[c];
    float var = eh2 - 2.f * a * mu * mu + a * a * mu * mu;
    float rstd = rsqrtf(var + 1e-5f);
    float w = gw[c] * rstd;
    float b = gb[c];
    float off = a * mu;
    int total = n * CC;
    for (int idx = blockIdx.x * 256 + threadIdx.x; idx < total; idx += gridDim.x * 256)
        out[idx] = (h[idx] - off) * w + b;
}

// ---------------------------------------------------------------------------
extern "C" void kernel_launch(void* const* d_in, const int* in_sizes, int n_in,
                              void* d_out, int out_size, void* d_ws, size_t ws_size,
                              hipStream_t stream) {
    const float* x0  = (const float*)d_in[0];
    const int*   ei  = (const int*)d_in[1];
    const float* Wl  = (const float*)d_in[2];
    const float* bl  = (const float*)d_in[3];
    const float* Wr  = (const float*)d_in[4];
    const float* br  = (const float*)d_in[5];
    const float* att = (const float*)d_in[6];
    const float* cb  = (const float*)d_in[7];
    const float* gw  = (const float*)d_in[8];
    const float* gs  = (const float*)d_in[9];
    const float* gb  = (const float*)d_in[10];

    const int n = in_sizes[0] / DD;      // 25000
    const int e = in_sizes[1] / 2;       // 400000
    const int* srcArr = ei;
    const int* dstArr = ei + e;

    // carve workspace
    char* w = (char*)d_ws;
    auto alloc = [&](size_t bytes) -> char* {
        char* p = w;
        w += (bytes + 255) & ~(size_t)255;
        return p;
    };
    __half* xl    = (__half*)alloc((size_t)n * HC * 2);
    float* xr     = (float*)alloc((size_t)n * HC * 4);
    float* hbuf   = (float*)alloc((size_t)n * CC * 4);
    float* xbuf   = (float*)alloc((size_t)n * CC * 4);
    int*   counts = (int*)  alloc((size_t)n * 4);
    int*   cursor = (int*)  alloc((size_t)n * 4);
    int*   rowptr = (int*)  alloc((size_t)(n + 1) * 4);
    int*   csr    = (int*)  alloc((size_t)(e + n) * 4);
    float* stats  = (float*)alloc(NLAY * 128 * 4);

    const int tot = e + n;
    hipLaunchKernelGGL(zero_kernel,  dim3((n + 255) / 256),   dim3(256), 0, stream,
                       counts, cursor, stats, n);
    hipLaunchKernelGGL(count_kernel, dim3((tot + 255) / 256), dim3(256), 0, stream,
                       dstArr, counts, e, n);
    hipLaunchKernelGGL(scan_kernel,  dim3(1), dim3(1024), 0, stream,
                       counts, rowptr, n);
    hipLaunchKernelGGL(fill_kernel,  dim3((tot + 255) / 256), dim3(256), 0, stream,
                       srcArr, dstArr, rowptr, cursor, csr, e, n);

    const float* xin = x0;
    for (int L = 0; L < NLAY; ++L) {
        hipLaunchKernelGGL(proj_kernel, dim3((n + 63) / 64, 4), dim3(256), 0, stream,
                           xin, Wl + (size_t)L * HC * DD, bl + L * HC,
                           Wr + (size_t)L * HC * DD, br + L * HC, xl, xr, n);
        hipLaunchKernelGGL(attn_kernel, dim3((n + 3) / 4), dim3(256), 0, stream,
                           xl, xr, att + L * HC, cb + L * CC, rowptr, csr, hbuf, n);
        hipLaunchKernelGGL(stats_kernel, dim3(128), dim3(256), 0, stream,
                           hbuf, stats + L * 128, n);
        float* xout = (L == NLAY - 1) ? (float*)d_out : xbuf;
        hipLaunchKernelGGL(norm_kernel, dim3(512), dim3(256), 0, stream,
                           hbuf, stats + L * 128, gw + L * CC, gs + L * CC, gb + L * CC,
                           xout, n);
        xin = xbuf;
    }
}

// Round 5
// 426.139 us; speedup vs baseline: 2.8267x; 1.2090x over previous
//
#include <hip/hip_runtime.h>
#include <hip/hip_fp16.h>
#include <math.h>

// Problem constants (GATv2, 3 layers, H=4 heads, C=64 channels, D=64 in-dim)
#define HC   256   // H*C
#define DD   64
#define NHD  4
#define CC   64
#define NLAY 3

typedef _Float16 h2 __attribute__((ext_vector_type(2)));

// ---------------------------------------------------------------------------
// zero counts/cursor/stats (ws is poisoned 0xAA before every call)
__global__ __launch_bounds__(256) void zero_kernel(int* __restrict__ counts,
                                                   int* __restrict__ cursor,
                                                   float* __restrict__ stats,
                                                   int n) {
    int i = blockIdx.x * 256 + threadIdx.x;
    if (i < n) { counts[i] = 0; cursor[i] = 0; }
    if (i < NLAY * 128) stats[i] = 0.f;
}

// histogram of destination nodes (self-loops appended implicitly)
__global__ __launch_bounds__(256) void count_kernel(const int* __restrict__ dstArr,
                                                    int* __restrict__ counts,
                                                    int e, int n) {
    int i = blockIdx.x * 256 + threadIdx.x;
    if (i >= e + n) return;
    int d = (i < e) ? dstArr[i] : (i - e);
    atomicAdd(&counts[d], 1);
}

// single-block exclusive scan -> rowptr[0..n]
__global__ __launch_bounds__(1024) void scan_kernel(const int* __restrict__ counts,
                                                    int* __restrict__ rowptr, int n) {
    __shared__ int ls[1024];
    int t = threadIdx.x;
    int chunk = (n + 1023) >> 10;
    int base = t * chunk;
    int local = 0;
    for (int i = 0; i < chunk; ++i) {
        int idx = base + i;
        if (idx < n) local += counts[idx];
    }
    ls[t] = local;
    __syncthreads();
    for (int off = 1; off < 1024; off <<= 1) {
        int v = (t >= off) ? ls[t - off] : 0;
        __syncthreads();
        ls[t] += v;
        __syncthreads();
    }
    int run = ls[t] - local;   // exclusive prefix for this thread's chunk
    for (int i = 0; i < chunk; ++i) {
        int idx = base + i;
        if (idx < n) { rowptr[idx] = run; run += counts[idx]; }
    }
    if (t == 1023) rowptr[n] = ls[1023];
}

// scatter edge sources into CSR slots grouped by destination
__global__ __launch_bounds__(256) void fill_kernel(const int* __restrict__ srcArr,
                                                   const int* __restrict__ dstArr,
                                                   const int* __restrict__ rowptr,
                                                   int* __restrict__ cursor,
                                                   int* __restrict__ csr_src,
                                                   int e, int n) {
    int i = blockIdx.x * 256 + threadIdx.x;
    if (i >= e + n) return;
    int s, d;
    if (i < e) { s = srcArr[i]; d = dstArr[i]; }
    else       { s = d = i - e; }
    int slot = rowptr[d] + atomicAdd(&cursor[d], 1);
    csr_src[slot] = s;
}

// ---------------------------------------------------------------------------
// xl = x @ Wl^T + bl ; xr = x @ Wr^T + br  (both stored fp16)
// Optional fused GraphNorm of the INPUT (stats/gn params of previous layer):
// y = h*a[c] + bb[c] applied during tile staging (stats==nullptr -> identity).
__global__ __launch_bounds__(256) void proj_kernel(const float* __restrict__ x,
                                                   const float* __restrict__ Wl,
                                                   const float* __restrict__ bl,
                                                   const float* __restrict__ Wr,
                                                   const float* __restrict__ br,
                                                   __half* __restrict__ xl,
                                                   __half* __restrict__ xr, int n,
                                                   const float* __restrict__ stats,
                                                   const float* __restrict__ pgw,
                                                   const float* __restrict__ pgs,
                                                   const float* __restrict__ pgb) {
    __shared__ float xs[64 * 64];        // x tile  [node][d] (normalized)
    __shared__ float wlT[64 * 65];       // Wl tile [d][c], pad 65 -> no conflicts
    __shared__ float wrT[64 * 65];
    __shared__ float nrm_a[64], nrm_b[64];
    const int t  = threadIdx.x;
    const int c  = t & 63;
    const int ty = t >> 6;
    const int n0 = blockIdx.x * 64;
    const int cb = blockIdx.y * 64;      // channel tile base (0,64,128,192)

    if (t < 64) {
        float a = 1.f, b = 0.f;
        if (stats) {
            float inv_n = 1.0f / (float)n;
            float mu  = stats[t] * inv_n;
            float eh2 = stats[64 + t] * inv_n;
            float al  = pgs[t];
            float var = eh2 - 2.f * al * mu * mu + al * al * mu * mu;
            float rstd = rsqrtf(var + 1e-5f);
            a = pgw[t] * rstd;
            b = pgb[t] - al * mu * a;
        }
        nrm_a[t] = a; nrm_b[t] = b;
    }
    __syncthreads();

    // stage x tile: 4096 contiguous floats, coalesced float4, norm fused
    {
        const float* xb = x + (size_t)n0 * DD;
        const int limit = (n - n0) * DD;               // valid floats in tile
        #pragma unroll
        for (int k = 0; k < 4; ++k) {
            int f = (k * 256 + t) * 4;                 // float index
            float4 v = make_float4(0.f, 0.f, 0.f, 0.f);
            if (f + 3 < limit) v = *(const float4*)(xb + f);
            else {                                     // ragged tail
                float tmp[4] = {0.f, 0.f, 0.f, 0.f};
                for (int q = 0; q < 4; ++q) if (f + q < limit) tmp[q] = xb[f + q];
                v = make_float4(tmp[0], tmp[1], tmp[2], tmp[3]);
            }
            const float4 a4 = *(const float4*)&nrm_a[f & 63];
            const float4 b4 = *(const float4*)&nrm_b[f & 63];
            v.x = fmaf(v.x, a4.x, b4.x);
            v.y = fmaf(v.y, a4.y, b4.y);
            v.z = fmaf(v.z, a4.z, b4.z);
            v.w = fmaf(v.w, a4.w, b4.w);
            *(float4*)&xs[f] = v;
        }
    }
    // stage W tiles transposed: flat f -> cc=f/64, dd=f%64 -> wT[dd*65+cc]
    {
        const float* wlb = Wl + (size_t)cb * DD;
        const float* wrb = Wr + (size_t)cb * DD;
        #pragma unroll
        for (int k = 0; k < 16; ++k) {
            int f = k * 256 + t;
            int ccc = f >> 6, ddd = f & 63;
            wlT[ddd * 65 + ccc] = wlb[f];
            wrT[ddd * 65 + ccc] = wrb[f];
        }
    }
    __syncthreads();

    float accl[16], accr[16];
    {
        const float bL = bl[cb + c], bR = br[cb + c];
        #pragma unroll
        for (int i = 0; i < 16; ++i) { accl[i] = bL; accr[i] = bR; }
    }
    const float* xrow = xs + ty * 16 * DD;
    for (int d4 = 0; d4 < DD; d4 += 4) {
        float4 xv[16];
        #pragma unroll
        for (int i = 0; i < 16; ++i)
            xv[i] = *(const float4*)(xrow + i * DD + d4);   // broadcast reads
        #pragma unroll
        for (int dd = 0; dd < 4; ++dd) {
            float wlv = wlT[(d4 + dd) * 65 + c];
            float wrv = wrT[(d4 + dd) * 65 + c];
            #pragma unroll
            for (int i = 0; i < 16; ++i) {
                float xvv = ((const float*)&xv[i])[dd];
                accl[i] = fmaf(xvv, wlv, accl[i]);
                accr[i] = fmaf(xvv, wrv, accr[i]);
            }
        }
    }
    #pragma unroll
    for (int i = 0; i < 16; ++i) {
        int node = n0 + ty * 16 + i;
        if (node < n) {
            xl[(size_t)node * HC + cb + c] = __float2half(accl[i]);
            xr[(size_t)node * HC + cb + c] = __float2half(accr[i]);
        }
    }
}

// ---------------------------------------------------------------------------
// per-node attention, ONE wave per node, TWO edges per iteration.
// lane l = e2*32 + h*8 + co : edge-slot e2, head h, channel-octet co (8 ch).
// Direct exp (no max subtraction: |logit| < ~10, fp32-safe) -> no loop-carried
// rescale chain. Packed fp16 (ext_vector _Float16 -> v_pk_*_f16) for logits;
// fp32 accumulators.
__global__ __launch_bounds__(256) void attn_kernel(const __half* __restrict__ xl,
                                                   const __half* __restrict__ xr,
                                                   const float* __restrict__ att,
                                                   const float* __restrict__ conv_bias,
                                                   const int* __restrict__ rowptr,
                                                   const int* __restrict__ csr_src,
                                                   float* __restrict__ h_out, int n) {
    const int wave = threadIdx.x >> 6;
    const int l    = threadIdx.x & 63;
    const int v    = blockIdx.x * 4 + wave;
    if (v >= n) return;

    const int e2 = l >> 5;
    const int h  = (l >> 3) & 3;
    const int co = l & 7;
    const int choff = h * CC + co * 8;             // channel offset in [0,256)

    // preload xr (fp16, 16B) and att (fp32 -> packed fp16)
    h2 xr2[4];
    *(uint4*)xr2 = *(const uint4*)(xr + (size_t)v * HC + choff);
    h2 at2[4];
    {
        const float* ap = att + choff;
        float4 a0 = *(const float4*)(ap);
        float4 a1 = *(const float4*)(ap + 4);
        at2[0] = (h2){(_Float16)a0.x, (_Float16)a0.y};
        at2[1] = (h2){(_Float16)a0.z, (_Float16)a0.w};
        at2[2] = (h2){(_Float16)a1.x, (_Float16)a1.y};
        at2[3] = (h2){(_Float16)a1.z, (_Float16)a1.w};
    }
    const _Float16 k02 = (_Float16)0.2f;

    const int rs = rowptr[v];
    const int re = rowptr[v + 1];

    float s = 0.f;
    float acc[8];
    #pragma unroll
    for (int q = 0; q < 8; ++q) acc[q] = 0.f;

    // prefetch first pair
    int kk0 = rs + e2;
    int j0  = csr_src[(kk0 < re) ? kk0 : rs];
    uint4 raw = *(const uint4*)(xl + (size_t)j0 * HC + choff);

    for (int k = rs; k < re; k += 2) {
        uint4 cur = raw;
        if (k + 2 < re) {
            int kk = k + 2 + e2;
            int jn = csr_src[(kk < re) ? kk : rs];
            raw = *(const uint4*)(xl + (size_t)jn * HC + choff);
        }
        const bool valid = (k + e2) < re;
        const h2* xh = (const h2*)&cur;

        h2 d2 = (h2){(_Float16)0.f, (_Float16)0.f};
        #pragma unroll
        for (int q = 0; q < 4; ++q) {
            h2 t  = xh[q] + xr2[q];
            h2 lk = __builtin_elementwise_max(t, t * k02);   // leaky_relu
            d2 += lk * at2[q];
        }
        float p = (float)d2.x + (float)d2.y;
        p += __shfl_xor(p, 1, 64);                      // reduce over 8-lane
        p += __shfl_xor(p, 2, 64);                      // channel-octet group
        p += __shfl_xor(p, 4, 64);

        float pe = valid ? __expf(p) : 0.f;
        s += pe;
        #pragma unroll
        for (int q = 0; q < 4; ++q) {
            float xf0 = (float)xh[q].x;
            float xf1 = (float)xh[q].y;
            acc[2 * q]     = fmaf(pe, xf0, acc[2 * q]);
            acc[2 * q + 1] = fmaf(pe, xf1, acc[2 * q + 1]);
        }
    }

    // combine edge slots, normalize per head, then head-mean
    s += __shfl_xor(s, 32, 64);
    const float inv = 1.f / s;                          // deg>=1 (self-loop)
    float out8[8];
    #pragma unroll
    for (int q = 0; q < 8; ++q) {
        float a = acc[q] + __shfl_xor(acc[q], 32, 64);
        a *= inv;
        a += __shfl_xor(a, 8, 64);                      // sum over heads
        a += __shfl_xor(a, 16, 64);
        out8[q] = 0.25f * a;
    }
    if (l < 8) {
        const float4 cb0 = *(const float4*)(conv_bias + co * 8);
        const float4 cb1 = *(const float4*)(conv_bias + co * 8 + 4);
        float4 o0 = make_float4(out8[0] + cb0.x, out8[1] + cb0.y,
                                out8[2] + cb0.z, out8[3] + cb0.w);
        float4 o1 = make_float4(out8[4] + cb1.x, out8[5] + cb1.y,
                                out8[6] + cb1.z, out8[7] + cb1.w);
        float* op = h_out + (size_t)v * CC + co * 8;
        *(float4*)op       = o0;
        *(float4*)(op + 4) = o1;
    }
}

// ---------------------------------------------------------------------------
// per-channel sum / sumsq over nodes (hierarchical, 128 blocks)
__global__ __launch_bounds__(256) void stats_kernel(const float* __restrict__ h,
                                                    float* __restrict__ stats, int n) {
    int t = threadIdx.x;
    int c = t & 63, r = t >> 6;
    float s = 0.f, s2 = 0.f;
    for (int node = blockIdx.x * 4 + r; node < n; node += gridDim.x * 4) {
        float v = h[node * CC + c];
        s += v; s2 += v * v;
    }
    __shared__ float l1[256], l2[256];
    l1[t] = s; l2[t] = s2;
    __syncthreads();
    if (t < 64) {
        s  = l1[t] + l1[64 + t] + l1[128 + t] + l1[192 + t];
        s2 = l2[t] + l2[64 + t] + l2[128 + t] + l2[192 + t];
        atomicAdd(&stats[c], s);
        atomicAdd(&stats[64 + c], s2);
    }
}

// GraphNorm (final layer only): x = (h - alpha*mu) * rsqrt(var+eps) * w + b
__global__ __launch_bounds__(256) void norm_kernel(const float* __restrict__ h,
                                                   const float* __restrict__ stats,
                                                   const float* __restrict__ gw,
                                                   const float* __restrict__ gs,
                                                   const float* __restrict__ gb,
                                                   float* __restrict__ out, int n) {
    int c = threadIdx.x & 63;
    float inv_n = 1.0f / (float)n;
    float mu  = stats[c] * inv_n;
    float eh2 = stats[64 + c] * inv_n;
    float a   = gs[c];
    float var = eh2 - 2.f * a * mu * mu + a * a * mu * mu;
    float rstd = rsqrtf(var + 1e-5f);
    float w = gw[c] * rstd;
    float b = gb[c];
    float off = a * mu;
    int total = n * CC;
    for (int idx = blockIdx.x * 256 + threadIdx.x; idx < total; idx += gridDim.x * 256)
        out[idx] = (h[idx] - off) * w + b;
}

// ---------------------------------------------------------------------------
extern "C" void kernel_launch(void* const* d_in, const int* in_sizes, int n_in,
                              void* d_out, int out_size, void* d_ws, size_t ws_size,
                              hipStream_t stream) {
    const float* x0  = (const float*)d_in[0];
    const int*   ei  = (const int*)d_in[1];
    const float* Wl  = (const float*)d_in[2];
    const float* bl  = (const float*)d_in[3];
    const float* Wr  = (const float*)d_in[4];
    const float* br  = (const float*)d_in[5];
    const float* att = (const float*)d_in[6];
    const float* cb  = (const float*)d_in[7];
    const float* gw  = (const float*)d_in[8];
    const float* gs  = (const float*)d_in[9];
    const float* gb  = (const float*)d_in[10];

    const int n = in_sizes[0] / DD;      // 25000
    const int e = in_sizes[1] / 2;       // 400000
    const int* srcArr = ei;
    const int* dstArr = ei + e;

    // carve workspace
    char* w = (char*)d_ws;
    auto alloc = [&](size_t bytes) -> char* {
        char* p = w;
        w += (bytes + 255) & ~(size_t)255;
        return p;
    };
    __half* xl    = (__half*)alloc((size_t)n * HC * 2);
    __half* xr    = (__half*)alloc((size_t)n * HC * 2);
    float* hbuf   = (float*)alloc((size_t)n * CC * 4);
    int*   counts = (int*)  alloc((size_t)n * 4);
    int*   cursor = (int*)  alloc((size_t)n * 4);
    int*   rowptr = (int*)  alloc((size_t)(n + 1) * 4);
    int*   csr    = (int*)  alloc((size_t)(e + n + 2) * 4);
    float* stats  = (float*)alloc(NLAY * 128 * 4);

    const int tot = e + n;
    hipLaunchKernelGGL(zero_kernel,  dim3((n + 255) / 256),   dim3(256), 0, stream,
                       counts, cursor, stats, n);
    hipLaunchKernelGGL(count_kernel, dim3((tot + 255) / 256), dim3(256), 0, stream,
                       dstArr, counts, e, n);
    hipLaunchKernelGGL(scan_kernel,  dim3(1), dim3(1024), 0, stream,
                       counts, rowptr, n);
    hipLaunchKernelGGL(fill_kernel,  dim3((tot + 255) / 256), dim3(256), 0, stream,
                       srcArr, dstArr, rowptr, cursor, csr, e, n);

    for (int L = 0; L < NLAY; ++L) {
        const float* xin = (L == 0) ? x0 : hbuf;
        const int Lp = (L == 0) ? 0 : L - 1;
        const float* st = (L == 0) ? nullptr : stats + (size_t)Lp * 128;
        hipLaunchKernelGGL(proj_kernel, dim3((n + 63) / 64, 4), dim3(256), 0, stream,
                           xin, Wl + (size_t)L * HC * DD, bl + L * HC,
                           Wr + (size_t)L * HC * DD, br + L * HC, xl, xr, n,
                           st, gw + Lp * CC, gs + Lp * CC, gb + Lp * CC);
        hipLaunchKernelGGL(attn_kernel, dim3((n + 3) / 4), dim3(256), 0, stream,
                           xl, xr, att + L * HC, cb + L * CC, rowptr, csr, hbuf, n);
        hipLaunchKernelGGL(stats_kernel, dim3(128), dim3(256), 0, stream,
                           hbuf, stats + L * 128, n);
    }
    hipLaunchKernelGGL(norm_kernel, dim3(512), dim3(256), 0, stream,
                       hbuf, stats + (NLAY - 1) * 128, gw + (NLAY - 1) * CC,
                       gs + (NLAY - 1) * CC, gb + (NLAY - 1) * CC,
                       (float*)d_out, n);
}

// Round 6
// 402.427 us; speedup vs baseline: 2.9933x; 1.0589x over previous
//
#include <hip/hip_runtime.h>
#include <hip/hip_fp16.h>
#include <math.h>

// Problem constants (GATv2, 3 layers, H=4 heads, C=64 channels, D=64 in-dim)
#define HC   256   // H*C
#define DD   64
#define NHD  4
#define CC   64
#define NLAY 3

typedef _Float16 h2 __attribute__((ext_vector_type(2)));
typedef _Float16 h4 __attribute__((ext_vector_type(4)));
typedef _Float16 h8 __attribute__((ext_vector_type(8)));
typedef float    f4 __attribute__((ext_vector_type(4)));

#define XSTR 72   // LDS row stride in halves: 144B = 16B-aligned, 2-way-free banks

// ---------------------------------------------------------------------------
// zero counts/cursor/stats (ws is poisoned 0xAA before every call)
__global__ __launch_bounds__(256) void zero_kernel(int* __restrict__ counts,
                                                   int* __restrict__ cursor,
                                                   float* __restrict__ stats,
                                                   int n) {
    int i = blockIdx.x * 256 + threadIdx.x;
    if (i < n) { counts[i] = 0; cursor[i] = 0; }
    if (i < NLAY * 128) stats[i] = 0.f;
}

// histogram of destination nodes (self-loops appended implicitly)
__global__ __launch_bounds__(256) void count_kernel(const int* __restrict__ dstArr,
                                                    int* __restrict__ counts,
                                                    int e, int n) {
    int i = blockIdx.x * 256 + threadIdx.x;
    if (i >= e + n) return;
    int d = (i < e) ? dstArr[i] : (i - e);
    atomicAdd(&counts[d], 1);
}

// single-block exclusive scan -> rowptr[0..n]
__global__ __launch_bounds__(1024) void scan_kernel(const int* __restrict__ counts,
                                                    int* __restrict__ rowptr, int n) {
    __shared__ int ls[1024];
    int t = threadIdx.x;
    int chunk = (n + 1023) >> 10;
    int base = t * chunk;
    int local = 0;
    for (int i = 0; i < chunk; ++i) {
        int idx = base + i;
        if (idx < n) local += counts[idx];
    }
    ls[t] = local;
    __syncthreads();
    for (int off = 1; off < 1024; off <<= 1) {
        int v = (t >= off) ? ls[t - off] : 0;
        __syncthreads();
        ls[t] += v;
        __syncthreads();
    }
    int run = ls[t] - local;   // exclusive prefix for this thread's chunk
    for (int i = 0; i < chunk; ++i) {
        int idx = base + i;
        if (idx < n) { rowptr[idx] = run; run += counts[idx]; }
    }
    if (t == 1023) rowptr[n] = ls[1023];
}

// scatter edge sources into CSR slots grouped by destination
__global__ __launch_bounds__(256) void fill_kernel(const int* __restrict__ srcArr,
                                                   const int* __restrict__ dstArr,
                                                   const int* __restrict__ rowptr,
                                                   int* __restrict__ cursor,
                                                   int* __restrict__ csr_src,
                                                   int e, int n) {
    int i = blockIdx.x * 256 + threadIdx.x;
    if (i >= e + n) return;
    int s, d;
    if (i < e) { s = srcArr[i]; d = dstArr[i]; }
    else       { s = d = i - e; }
    int slot = rowptr[d] + atomicAdd(&cursor[d], 1);
    csr_src[slot] = s;
}

// ---------------------------------------------------------------------------
// MFMA projection: out = x @ W^T + b, fp16 in/out, fp32 accumulate.
// grid (ceil(n/64), 2): y=0 -> Wl/bl -> xl ; y=1 -> Wr/br -> xr.
// Block 256 thr = 4 waves; wave w computes nodes n0+16w..+15 x all 256 ch
// via 16 (16x16) tiles, 2 MFMAs (K=32 each) per tile.
// Fused GraphNorm of the INPUT (prev layer stats; stats==nullptr -> identity).
__global__ __launch_bounds__(256) void proj_kernel(const float* __restrict__ x,
                                                   const float* __restrict__ Wl,
                                                   const float* __restrict__ bl,
                                                   const float* __restrict__ Wr,
                                                   const float* __restrict__ br,
                                                   __half* __restrict__ xl,
                                                   __half* __restrict__ xr, int n,
                                                   const float* __restrict__ stats,
                                                   const float* __restrict__ pgw,
                                                   const float* __restrict__ pgs,
                                                   const float* __restrict__ pgb) {
    __shared__ _Float16 xs[64 * XSTR];    // x tile  [node][d], fp16
    __shared__ _Float16 ws[256 * XSTR];   // W       [ch][d],   fp16
    __shared__ float nrm_a[64], nrm_b[64];
    const int t  = threadIdx.x;
    const int n0 = blockIdx.x * 64;
    const float* Wsel = blockIdx.y ? Wr : Wl;
    const float* bsel = blockIdx.y ? br : bl;
    __half*      osel = blockIdx.y ? xr : xl;

    if (t < 64) {
        float a = 1.f, b = 0.f;
        if (stats) {
            float inv_n = 1.0f / (float)n;
            float mu  = stats[t] * inv_n;
            float eh2 = stats[64 + t] * inv_n;
            float al  = pgs[t];
            float var = eh2 - 2.f * al * mu * mu + al * al * mu * mu;
            float rstd = rsqrtf(var + 1e-5f);
            a = pgw[t] * rstd;
            b = pgb[t] - al * mu * a;
        }
        nrm_a[t] = a; nrm_b[t] = b;
    }
    __syncthreads();

    // stage x tile (fp32 -> norm -> fp16), coalesced float4
    {
        const float* xb = x + (size_t)n0 * DD;
        const int limit = (n - n0) * DD;
        #pragma unroll
        for (int it = 0; it < 4; ++it) {
            int f = (it * 256 + t) * 4;
            float4 v = make_float4(0.f, 0.f, 0.f, 0.f);
            if (f + 3 < limit) v = *(const float4*)(xb + f);
            else {
                float tmp[4] = {0.f, 0.f, 0.f, 0.f};
                for (int q = 0; q < 4; ++q) if (f + q < limit) tmp[q] = xb[f + q];
                v = make_float4(tmp[0], tmp[1], tmp[2], tmp[3]);
            }
            int d = f & 63;
            const float4 a4 = *(const float4*)&nrm_a[d];
            const float4 b4 = *(const float4*)&nrm_b[d];
            h4 hv;
            hv.x = (_Float16)fmaf(v.x, a4.x, b4.x);
            hv.y = (_Float16)fmaf(v.y, a4.y, b4.y);
            hv.z = (_Float16)fmaf(v.z, a4.z, b4.z);
            hv.w = (_Float16)fmaf(v.w, a4.w, b4.w);
            *(h4*)&xs[(f >> 6) * XSTR + d] = hv;
        }
    }
    // stage W (fp32 -> fp16): 256x64 floats = 16 passes of 1024 float4-lanes
    {
        #pragma unroll
        for (int it = 0; it < 16; ++it) {
            int f = (it * 256 + t) * 4;
            float4 v = *(const float4*)(Wsel + f);
            h4 hv = { (_Float16)v.x, (_Float16)v.y, (_Float16)v.z, (_Float16)v.w };
            *(h4*)&ws[(f >> 6) * XSTR + (f & 63)] = hv;
        }
    }
    __syncthreads();

    const int w    = t >> 6;
    const int lane = t & 63;
    const int m    = lane & 15;          // A row / B col / C col index
    const int q    = lane >> 4;          // quad: k-group / C row group

    const _Float16* arow = xs + (w * 16 + m) * XSTR + q * 8;
    const h8 A0 = *(const h8*)arow;            // k = q*8 .. +7
    const h8 A1 = *(const h8*)(arow + 32);     // k = 32 + q*8 .. +7

    f4 acc[16];
    #pragma unroll
    for (int ct = 0; ct < 16; ++ct) {
        const _Float16* brow = ws + (ct * 16 + m) * XSTR + q * 8;
        const h8 B0 = *(const h8*)brow;
        const h8 B1 = *(const h8*)(brow + 32);
        f4 c = {0.f, 0.f, 0.f, 0.f};
        c = __builtin_amdgcn_mfma_f32_16x16x32_f16(A0, B0, c, 0, 0, 0);
        c = __builtin_amdgcn_mfma_f32_16x16x32_f16(A1, B1, c, 0, 0, 0);
        acc[ct] = c;
    }

    // epilogue: C/D layout col=lane&15 (ch), row=q*4+reg (node)
    #pragma unroll
    for (int ct = 0; ct < 16; ++ct) {
        int ch = ct * 16 + m;
        float bv = bsel[ch];
        #pragma unroll
        for (int r = 0; r < 4; ++r) {
            int node = n0 + w * 16 + q * 4 + r;
            if (node < n)
                osel[(size_t)node * HC + ch] = __float2half(acc[ct][r] + bv);
        }
    }
}

// ---------------------------------------------------------------------------
// per-node attention, ONE wave per node, TWO edges per iteration.
// lane l = e2*32 + h*8 + co : edge-slot e2, head h, channel-octet co (8 ch).
// Direct exp (no max subtraction: |logit| < ~10, fp32-safe) -> no loop-carried
// rescale chain. Packed fp16 (ext_vector _Float16 -> v_pk_*_f16) for logits;
// fp32 accumulators.
__global__ __launch_bounds__(256) void attn_kernel(const __half* __restrict__ xl,
                                                   const __half* __restrict__ xr,
                                                   const float* __restrict__ att,
                                                   const float* __restrict__ conv_bias,
                                                   const int* __restrict__ rowptr,
                                                   const int* __restrict__ csr_src,
                                                   float* __restrict__ h_out, int n) {
    const int wave = threadIdx.x >> 6;
    const int l    = threadIdx.x & 63;
    const int v    = blockIdx.x * 4 + wave;
    if (v >= n) return;

    const int e2 = l >> 5;
    const int h  = (l >> 3) & 3;
    const int co = l & 7;
    const int choff = h * CC + co * 8;             // channel offset in [0,256)

    // preload xr (fp16, 16B) and att (fp32 -> packed fp16)
    h2 xr2[4];
    *(uint4*)xr2 = *(const uint4*)(xr + (size_t)v * HC + choff);
    h2 at2[4];
    {
        const float* ap = att + choff;
        float4 a0 = *(const float4*)(ap);
        float4 a1 = *(const float4*)(ap + 4);
        at2[0] = (h2){(_Float16)a0.x, (_Float16)a0.y};
        at2[1] = (h2){(_Float16)a0.z, (_Float16)a0.w};
        at2[2] = (h2){(_Float16)a1.x, (_Float16)a1.y};
        at2[3] = (h2){(_Float16)a1.z, (_Float16)a1.w};
    }
    const _Float16 k02 = (_Float16)0.2f;

    const int rs = rowptr[v];
    const int re = rowptr[v + 1];

    float s = 0.f;
    float acc[8];
    #pragma unroll
    for (int q = 0; q < 8; ++q) acc[q] = 0.f;

    // prefetch first pair
    int kk0 = rs + e2;
    int j0  = csr_src[(kk0 < re) ? kk0 : rs];
    uint4 raw = *(const uint4*)(xl + (size_t)j0 * HC + choff);

    for (int k = rs; k < re; k += 2) {
        uint4 cur = raw;
        if (k + 2 < re) {
            int kk = k + 2 + e2;
            int jn = csr_src[(kk < re) ? kk : rs];
            raw = *(const uint4*)(xl + (size_t)jn * HC + choff);
        }
        const bool valid = (k + e2) < re;
        const h2* xh = (const h2*)&cur;

        h2 d2 = (h2){(_Float16)0.f, (_Float16)0.f};
        #pragma unroll
        for (int q = 0; q < 4; ++q) {
            h2 t  = xh[q] + xr2[q];
            h2 lk = __builtin_elementwise_max(t, t * k02);   // leaky_relu
            d2 += lk * at2[q];
        }
        float p = (float)d2.x + (float)d2.y;
        p += __shfl_xor(p, 1, 64);                      // reduce over 8-lane
        p += __shfl_xor(p, 2, 64);                      // channel-octet group
        p += __shfl_xor(p, 4, 64);

        float pe = valid ? __expf(p) : 0.f;
        s += pe;
        #pragma unroll
        for (int q = 0; q < 4; ++q) {
            float xf0 = (float)xh[q].x;
            float xf1 = (float)xh[q].y;
            acc[2 * q]     = fmaf(pe, xf0, acc[2 * q]);
            acc[2 * q + 1] = fmaf(pe, xf1, acc[2 * q + 1]);
        }
    }

    // combine edge slots, normalize per head, then head-mean
    s += __shfl_xor(s, 32, 64);
    const float inv = 1.f / s;                          // deg>=1 (self-loop)
    float out8[8];
    #pragma unroll
    for (int q = 0; q < 8; ++q) {
        float a = acc[q] + __shfl_xor(acc[q], 32, 64);
        a *= inv;
        a += __shfl_xor(a, 8, 64);                      // sum over heads
        a += __shfl_xor(a, 16, 64);
        out8[q] = 0.25f * a;
    }
    if (l < 8) {
        const float4 cb0 = *(const float4*)(conv_bias + co * 8);
        const float4 cb1 = *(const float4*)(conv_bias + co * 8 + 4);
        float4 o0 = make_float4(out8[0] + cb0.x, out8[1] + cb0.y,
                                out8[2] + cb0.z, out8[3] + cb0.w);
        float4 o1 = make_float4(out8[4] + cb1.x, out8[5] + cb1.y,
                                out8[6] + cb1.z, out8[7] + cb1.w);
        float* op = h_out + (size_t)v * CC + co * 8;
        *(float4*)op       = o0;
        *(float4*)(op + 4) = o1;
    }
}

// ---------------------------------------------------------------------------
// per-channel sum / sumsq over nodes (hierarchical, 128 blocks)
__global__ __launch_bounds__(256) void stats_kernel(const float* __restrict__ h,
                                                    float* __restrict__ stats, int n) {
    int t = threadIdx.x;
    int c = t & 63, r = t >> 6;
    float s = 0.f, s2 = 0.f;
    for (int node = blockIdx.x * 4 + r; node < n; node += gridDim.x * 4) {
        float v = h[node * CC + c];
        s += v; s2 += v * v;
    }
    __shared__ float l1[256], l2[256];
    l1[t] = s; l2[t] = s2;
    __syncthreads();
    if (t < 64) {
        s  = l1[t] + l1[64 + t] + l1[128 + t] + l1[192 + t];
        s2 = l2[t] + l2[64 + t] + l2[128 + t] + l2[192 + t];
        atomicAdd(&stats[c], s);
        atomicAdd(&stats[64 + c], s2);
    }
}

// GraphNorm (final layer only): x = (h - alpha*mu) * rsqrt(var+eps) * w + b
__global__ __launch_bounds__(256) void norm_kernel(const float* __restrict__ h,
                                                   const float* __restrict__ stats,
                                                   const float* __restrict__ gw,
                                                   const float* __restrict__ gs,
                                                   const float* __restrict__ gb,
                                                   float* __restrict__ out, int n) {
    int c = threadIdx.x & 63;
    float inv_n = 1.0f / (float)n;
    float mu  = stats[c] * inv_n;
    float eh2 = stats[64 + c] * inv_n;
    float a   = gs[c];
    float var = eh2 - 2.f * a * mu * mu + a * a * mu * mu;
    float rstd = rsqrtf(var + 1e-5f);
    float w = gw[c] * rstd;
    float b = gb[c];
    float off = a * mu;
    int total = n * CC;
    for (int idx = blockIdx.x * 256 + threadIdx.x; idx < total; idx += gridDim.x * 256)
        out[idx] = (h[idx] - off) * w + b;
}

// ---------------------------------------------------------------------------
extern "C" void kernel_launch(void* const* d_in, const int* in_sizes, int n_in,
                              void* d_out, int out_size, void* d_ws, size_t ws_size,
                              hipStream_t stream) {
    const float* x0  = (const float*)d_in[0];
    const int*   ei  = (const int*)d_in[1];
    const float* Wl  = (const float*)d_in[2];
    const float* bl  = (const float*)d_in[3];
    const float* Wr  = (const float*)d_in[4];
    const float* br  = (const float*)d_in[5];
    const float* att = (const float*)d_in[6];
    const float* cb  = (const float*)d_in[7];
    const float* gw  = (const float*)d_in[8];
    const float* gs  = (const float*)d_in[9];
    const float* gb  = (const float*)d_in[10];

    const int n = in_sizes[0] / DD;      // 25000
    const int e = in_sizes[1] / 2;       // 400000
    const int* srcArr = ei;
    const int* dstArr = ei + e;

    // carve workspace
    char* w = (char*)d_ws;
    auto alloc = [&](size_t bytes) -> char* {
        char* p = w;
        w += (bytes + 255) & ~(size_t)255;
        return p;
    };
    __half* xl    = (__half*)alloc((size_t)n * HC * 2);
    __half* xr    = (__half*)alloc((size_t)n * HC * 2);
    float* hbuf   = (float*)alloc((size_t)n * CC * 4);
    int*   counts = (int*)  alloc((size_t)n * 4);
    int*   cursor = (int*)  alloc((size_t)n * 4);
    int*   rowptr = (int*)  alloc((size_t)(n + 1) * 4);
    int*   csr    = (int*)  alloc((size_t)(e + n + 2) * 4);
    float* stats  = (float*)alloc(NLAY * 128 * 4);

    const int tot = e + n;
    hipLaunchKernelGGL(zero_kernel,  dim3((n + 255) / 256),   dim3(256), 0, stream,
                       counts, cursor, stats, n);
    hipLaunchKernelGGL(count_kernel, dim3((tot + 255) / 256), dim3(256), 0, stream,
                       dstArr, counts, e, n);
    hipLaunchKernelGGL(scan_kernel,  dim3(1), dim3(1024), 0, stream,
                       counts, rowptr, n);
    hipLaunchKernelGGL(fill_kernel,  dim3((tot + 255) / 256), dim3(256), 0, stream,
                       srcArr, dstArr, rowptr, cursor, csr, e, n);

    for (int L = 0; L < NLAY; ++L) {
        const float* xin = (L == 0) ? x0 : hbuf;
        const int Lp = (L == 0) ? 0 : L - 1;
        const float* st = (L == 0) ? nullptr : stats + (size_t)Lp * 128;
        hipLaunchKernelGGL(proj_kernel, dim3((n + 63) / 64, 2), dim3(256), 0, stream,
                           xin, Wl + (size_t)L * HC * DD, bl + L * HC,
                           Wr + (size_t)L * HC * DD, br + L * HC, xl, xr, n,
                           st, gw + Lp * CC, gs + Lp * CC, gb + Lp * CC);
        hipLaunchKernelGGL(attn_kernel, dim3((n + 3) / 4), dim3(256), 0, stream,
                           xl, xr, att + L * HC, cb + L * CC, rowptr, csr, hbuf, n);
        hipLaunchKernelGGL(stats_kernel, dim3(128), dim3(256), 0, stream,
                           hbuf, stats + L * 128, n);
    }
    hipLaunchKernelGGL(norm_kernel, dim3(512), dim3(256), 0, stream,
                       hbuf, stats + (NLAY - 1) * 128, gw + (NLAY - 1) * CC,
                       gs + (NLAY - 1) * CC, gb + (NLAY - 1) * CC,
                       (float*)d_out, n);
}